// Round 6
// baseline (460.215 us; speedup 1.0000x reference)
//
#include <hip/hip_runtime.h>
#include <hip/hip_bf16.h>
#include <float.h>
#include <math.h>

#define BB 8
#define NN 4096
#define CC 128
#define MROWS (BB * NN)   // 32768
#define EPSBN 1e-5f

#define QB 64             // queries per knn block
#define CT 64             // candidates per tile
#define NTILE (NN / CT)   // 64

typedef __attribute__((ext_vector_type(8))) short bf16x8;
typedef __attribute__((ext_vector_type(4))) float f32x4;

#define GLOBAL_AS __attribute__((address_space(1)))
#define LDS_AS __attribute__((address_space(3)))

__device__ __forceinline__ ushort f2bf(float f) {
  uint u = __float_as_uint(f);
  u = u + 0x7fffu + ((u >> 16) & 1u);   // RNE
  return (ushort)(u >> 16);
}
__device__ __forceinline__ float bf2f(ushort h) {
  return __uint_as_float(((uint)h) << 16);
}

// ---------------------------------------------------------------------------
// fp32 GEMM: out[M,128] = A[M,K] @ W[K,128] + bias, with fused column stats
// (sum/sumsq per output channel via LDS reduce + 2 global atomics per col).
// ---------------------------------------------------------------------------
#define GBM 64
#define GBN 128
#define GBK 32

__global__ __launch_bounds__(256)
void gemm_bias_stats_kernel(const float* __restrict__ A, const float* __restrict__ W,
                            const float* __restrict__ bias, float* __restrict__ out,
                            int M, int K, float* __restrict__ sum,
                            float* __restrict__ sumsq) {
  __shared__ float As[GBK][GBM + 4];
  __shared__ float Ws[GBK][GBN + 4];
  __shared__ float redS[GBN], redS2[GBN];
  int tid = threadIdx.x;
  int m0 = blockIdx.x * GBM;
  int ty = tid >> 4, tx = tid & 15;
  if (tid < GBN) { redS[tid] = 0.f; redS2[tid] = 0.f; }

  float acc[4][8];
#pragma unroll
  for (int i = 0; i < 4; ++i)
#pragma unroll
    for (int j = 0; j < 8; ++j) acc[i][j] = 0.f;

  for (int k0 = 0; k0 < K; k0 += GBK) {
    {
      int row = tid >> 2, ch = tid & 3;
      const float* ap = A + (long)(m0 + row) * K + k0 + ch * 8;
      float4 a0 = *(const float4*)ap;
      float4 a1 = *(const float4*)(ap + 4);
      float av2[8] = {a0.x, a0.y, a0.z, a0.w, a1.x, a1.y, a1.z, a1.w};
#pragma unroll
      for (int e = 0; e < 8; ++e) As[ch * 8 + e][row] = av2[e];
    }
#pragma unroll
    for (int c = 0; c < 4; ++c) {
      int lin = tid + 256 * c;
      int row = lin >> 5, c4 = (lin & 31) * 4;
      *(float4*)&Ws[row][c4] = *(const float4*)&W[(long)(k0 + row) * GBN + c4];
    }
    __syncthreads();
#pragma unroll
    for (int kk = 0; kk < GBK; ++kk) {
      float4 a4 = *(const float4*)&As[kk][ty * 4];
      float4 b0 = *(const float4*)&Ws[kk][tx * 8];
      float4 b1 = *(const float4*)&Ws[kk][tx * 8 + 4];
      float av[4] = {a4.x, a4.y, a4.z, a4.w};
      float bv[8] = {b0.x, b0.y, b0.z, b0.w, b1.x, b1.y, b1.z, b1.w};
#pragma unroll
      for (int i = 0; i < 4; ++i)
#pragma unroll
        for (int j = 0; j < 8; ++j)
          acc[i][j] = fmaf(av[i], bv[j], acc[i][j]);
    }
    __syncthreads();
  }
  float bi[8];
  *(float4*)&bi[0] = *(const float4*)&bias[tx * 8];
  *(float4*)&bi[4] = *(const float4*)&bias[tx * 8 + 4];
  float cs[8], css[8];
#pragma unroll
  for (int j = 0; j < 8; ++j) { cs[j] = 0.f; css[j] = 0.f; }
#pragma unroll
  for (int i = 0; i < 4; ++i) {
    long r = (long)(m0 + ty * 4 + i);
    float o[8];
#pragma unroll
    for (int j = 0; j < 8; ++j) {
      o[j] = acc[i][j] + bi[j];
      cs[j] += o[j];
      css[j] += o[j] * o[j];
    }
    float4 o0 = {o[0], o[1], o[2], o[3]};
    float4 o1 = {o[4], o[5], o[6], o[7]};
    *(float4*)&out[r * GBN + tx * 8] = o0;
    *(float4*)&out[r * GBN + tx * 8 + 4] = o1;
  }
#pragma unroll
  for (int j = 0; j < 8; ++j) {
    atomicAdd(&redS[tx * 8 + j], cs[j]);
    atomicAdd(&redS2[tx * 8 + j], css[j]);
  }
  __syncthreads();
  if (tid < GBN) {
    atomicAdd(&sum[tid], redS[tid]);
    atomicAdd(&sumsq[tid], redS2[tid]);
  }
}

// ---------------------------------------------------------------------------
// BN apply (stage 1) + h into cat[:, :128] + bf16 hi/lo split + row sq-norms
// ---------------------------------------------------------------------------
__global__ __launch_bounds__(256)
void bn_split_kernel(const float* __restrict__ X, const float* __restrict__ sum,
                     const float* __restrict__ sumsq, const float* __restrict__ g,
                     const float* __restrict__ be, float* __restrict__ cat,
                     ushort* __restrict__ hHi, ushort* __restrict__ hLo,
                     float* __restrict__ sqv) {
  int gid = blockIdx.x * 256 + threadIdx.x;   // quad id
  int row = gid >> 5;
  int c4 = (gid & 31) * 4;
  const float inv = 1.0f / (float)MROWS;
  float4 x  = *(const float4*)&X[(long)row * CC + c4];
  float4 sm = *(const float4*)&sum[c4];
  float4 sq = *(const float4*)&sumsq[c4];
  float4 gv = *(const float4*)&g[c4];
  float4 bv = *(const float4*)&be[c4];
  float xv[4] = {x.x, x.y, x.z, x.w};
  float smv[4] = {sm.x, sm.y, sm.z, sm.w};
  float sqv2[4] = {sq.x, sq.y, sq.z, sq.w};
  float ga[4] = {gv.x, gv.y, gv.z, gv.w};
  float ba[4] = {bv.x, bv.y, bv.z, bv.w};
  float h[4];
  ushort hi[4], lo[4];
#pragma unroll
  for (int e = 0; e < 4; ++e) {
    float m = smv[e] * inv;
    float v = sqv2[e] * inv - m * m;
    float sc = ga[e] * rsqrtf(v + EPSBN);
    h[e] = (xv[e] - m) * sc + ba[e];
    hi[e] = f2bf(h[e]);
    lo[e] = f2bf(h[e] - bf2f(hi[e]));
  }
  float4 hv = {h[0], h[1], h[2], h[3]};
  *(float4*)&cat[(long)row * 256 + c4] = hv;
  ushort4 h4 = {hi[0], hi[1], hi[2], hi[3]};
  ushort4 l4 = {lo[0], lo[1], lo[2], lo[3]};
  *(ushort4*)&hHi[(long)row * CC + c4] = h4;
  *(ushort4*)&hLo[(long)row * CC + c4] = l4;
  // fused row squared-norm: 32 threads per row (within one 32-lane half)
  float s = h[0] * h[0] + h[1] * h[1] + h[2] * h[2] + h[3] * h[3];
#pragma unroll
  for (int off = 16; off >= 1; off >>= 1) s += __shfl_xor(s, off, 64);
  if ((threadIdx.x & 31) == 0) sqv[row] = s;
}

// ---------------------------------------------------------------------------
// top-9 sorted insert (fully unrolled predicated network, stays in registers)
// ---------------------------------------------------------------------------
__device__ __forceinline__ void insert9(float (&dk)[9], int (&ik)[9], float s, int idx) {
  bool sh[9];
#pragma unroll
  for (int k = 0; k < 9; ++k) sh[k] = s < dk[k];
#pragma unroll
  for (int k = 8; k >= 1; --k) {
    if (sh[k]) {
      bool up = sh[k - 1];
      dk[k] = up ? dk[k - 1] : s;
      ik[k] = up ? ik[k - 1] : idx;
    }
  }
  if (sh[0]) { dk[0] = s; ik[0] = idx; }
}

__device__ __forceinline__ void insert9_lex(float (&dk)[9], int (&ik)[9], float pd, int pi) {
  bool ins = (pd < dk[8]) || (pd == dk[8] && pi < ik[8]);
  if (ins) {
    bool sh[9];
#pragma unroll
    for (int t = 0; t < 9; ++t)
      sh[t] = (pd < dk[t]) || (pd == dk[t] && pi < ik[t]);
#pragma unroll
    for (int t = 8; t >= 1; --t) {
      if (sh[t]) {
        bool up = sh[t - 1];
        dk[t] = up ? dk[t - 1] : pd;
        ik[t] = up ? ik[t - 1] : pi;
      }
    }
    if (sh[0]) { dk[0] = pd; ik[0] = pi; }
  }
}

// ---------------------------------------------------------------------------
// Fused: pairwise dist (split-bf16, 3 MFMA passes) + top-9 + max-relative agg
// Block = 64 queries (512 blocks, blockIdx&7 = batch for XCD-L2 locality).
// 2x2 wave grid: wave (wq,wc) computes queries wq*32..+31 x candidates
// wc*32..+31 -> A-file is only 16 bf16x8 = 64 VGPRs per wave, so it stays
// register-resident (R5's 128-VGPR A-file was rematerialized from global
// every tile -> VALUBusy 44%). Candidate staging via global_load_lds DMA
// into XOR-swizzled LDS layout: chunk(r,d) at slot s = r*16 + (d^(r&7)).
// ---------------------------------------------------------------------------
#define SCST 68   // scoreT stride (floats)

__global__ __attribute__((amdgpu_flat_work_group_size(256, 256), amdgpu_waves_per_eu(2, 2)))
void knn_agg_kernel(const ushort* __restrict__ hHi, const ushort* __restrict__ hLo,
                    const float* __restrict__ sqv, const float* __restrict__ cat,
                    float* __restrict__ catw) {
  __shared__ ushort csHi[CT * 128];       // 16 KB, swizzled chunk order
  __shared__ ushort csLo[CT * 128];       // 16 KB
  __shared__ float  scoreT[CT * SCST];    // [cand][query], 17.4 KB

  int tid = threadIdx.x;
  int wave = tid >> 6, lane = tid & 63;
  int l15 = lane & 15, quad = lane >> 4;
  int wq = wave >> 1, wc = wave & 1;
  int b = blockIdx.x & 7, qt = blockIdx.x >> 3;
  long brow = (long)b * NN;
  long rowbase = brow + (long)qt * QB;

  // persistent A-fragments: this wave's 32 queries, hi+lo (64 VGPRs)
  bf16x8 aHi[2][4], aLo[2][4];
#pragma unroll
  for (int rg = 0; rg < 2; ++rg) {
    long gq = rowbase + wq * 32 + rg * 16 + l15;
    const ushort* ph = hHi + gq * CC + quad * 8;
    const ushort* pl = hLo + gq * CC + quad * 8;
#pragma unroll
    for (int ks = 0; ks < 4; ++ks) {
      aHi[rg][ks] = *(const bf16x8*)(ph + ks * 32);
      aLo[rg][ks] = *(const bf16x8*)(pl + ks * 32);
    }
  }

  // per-lane DMA source offsets (ushort units), constant across tiles
  int srcOff[4];
#pragma unroll
  for (int it = 0; it < 4; ++it) {
    int s = (wave * 4 + it) * 64 + lane;
    int r = s >> 4, dp = s & 15;
    int d = dp ^ (r & 7);
    srcOff[it] = r * CC + d * 8;
  }

  float dk[9]; int ik[9];
#pragma unroll
  for (int k = 0; k < 9; ++k) { dk[k] = FLT_MAX; ik[k] = 0x7FFFFFFF; }
  int q = tid & 63, quarter = tid >> 6;

  // ---- prologue: DMA tile 0 into LDS ----
  {
    const ushort* baseH = hHi + brow * CC;
    const ushort* baseL = hLo + brow * CC;
#pragma unroll
    for (int it = 0; it < 4; ++it) {
      int s0 = (wave * 4 + it) * 64;
      __builtin_amdgcn_global_load_lds((const GLOBAL_AS void*)(baseH + srcOff[it]),
                                       (LDS_AS void*)&csHi[s0 * 8], 16, 0, 0);
      __builtin_amdgcn_global_load_lds((const GLOBAL_AS void*)(baseL + srcOff[it]),
                                       (LDS_AS void*)&csLo[s0 * 8], 16, 0, 0);
    }
  }
  __syncthreads();   // vmcnt(0) drain -> tile 0 resident

#pragma unroll 1
  for (int ct = 0; ct < NTILE; ++ct) {
    // ---- MFMA: this wave's 32 candidates x 32 queries ----
    float sqc[2];
#pragma unroll
    for (int cg = 0; cg < 2; ++cg)
      sqc[cg] = sqv[brow + (long)ct * CT + wc * 32 + cg * 16 + l15];
    f32x4 ac[2][2];
#pragma unroll
    for (int cg = 0; cg < 2; ++cg)
#pragma unroll
      for (int rg = 0; rg < 2; ++rg) { ac[cg][rg].x = 0.f; ac[cg][rg].y = 0.f; ac[cg][rg].z = 0.f; ac[cg][rg].w = 0.f; }
#pragma unroll
    for (int ks = 0; ks < 4; ++ks) {
      bf16x8 bHi[2], bLo[2];
#pragma unroll
      for (int cg = 0; cg < 2; ++cg) {
        int crow = wc * 32 + cg * 16 + l15;
        int sb = crow * 16 + ((ks * 4 + quad) ^ (crow & 7));
        bHi[cg] = *(const bf16x8*)&csHi[sb * 8];
        bLo[cg] = *(const bf16x8*)&csLo[sb * 8];
      }
#pragma unroll
      for (int cg = 0; cg < 2; ++cg)
#pragma unroll
        for (int rg = 0; rg < 2; ++rg) {
          ac[cg][rg] = __builtin_amdgcn_mfma_f32_16x16x32_bf16(aHi[rg][ks], bHi[cg], ac[cg][rg], 0, 0, 0);
          ac[cg][rg] = __builtin_amdgcn_mfma_f32_16x16x32_bf16(aHi[rg][ks], bLo[cg], ac[cg][rg], 0, 0, 0);
          ac[cg][rg] = __builtin_amdgcn_mfma_f32_16x16x32_bf16(aLo[rg][ks], bHi[cg], ac[cg][rg], 0, 0, 0);
        }
    }
#pragma unroll
    for (int cg = 0; cg < 2; ++cg) {
      int crow = wc * 32 + cg * 16 + l15;
#pragma unroll
      for (int rg = 0; rg < 2; ++rg) {
        float4 o = {fmaf(-2.f, ac[cg][rg].x, sqc[cg]), fmaf(-2.f, ac[cg][rg].y, sqc[cg]),
                    fmaf(-2.f, ac[cg][rg].z, sqc[cg]), fmaf(-2.f, ac[cg][rg].w, sqc[cg])};
        *(float4*)&scoreT[crow * SCST + wq * 32 + rg * 16 + quad * 4] = o;
      }
    }
    __syncthreads();   // scores ready; cs(ct) fully consumed

    // ---- issue DMA for tile ct+1 (in flight during scan) ----
    {
      int nt = (ct + 1) & (NTILE - 1);
      const ushort* baseH = hHi + (brow + (long)nt * CT) * CC;
      const ushort* baseL = hLo + (brow + (long)nt * CT) * CC;
#pragma unroll
      for (int it = 0; it < 4; ++it) {
        int s0 = (wave * 4 + it) * 64;
        __builtin_amdgcn_global_load_lds((const GLOBAL_AS void*)(baseH + srcOff[it]),
                                         (LDS_AS void*)&csHi[s0 * 8], 16, 0, 0);
        __builtin_amdgcn_global_load_lds((const GLOBAL_AS void*)(baseL + srcOff[it]),
                                         (LDS_AS void*)&csLo[s0 * 8], 16, 0, 0);
      }
    }

    // ---- scan: thread (q, quarter) scans candidates quarter*16..+15 ----
    int gbase = ct * CT + quarter * 16;
    const float* scol = &scoreT[(quarter * 16) * SCST + q];
    float thr = dk[8];
#pragma unroll
    for (int jj = 0; jj < 16; jj += 4) {
      float s0 = scol[(jj + 0) * SCST];
      float s1 = scol[(jj + 1) * SCST];
      float s2 = scol[(jj + 2) * SCST];
      float s3 = scol[(jj + 3) * SCST];
      float mn = fminf(fminf(s0, s1), fminf(s2, s3));
      if (mn < thr) {
        if (s0 < thr) { insert9(dk, ik, s0, gbase + jj + 0); thr = dk[8]; }
        if (s1 < thr) { insert9(dk, ik, s1, gbase + jj + 1); thr = dk[8]; }
        if (s2 < thr) { insert9(dk, ik, s2, gbase + jj + 2); thr = dk[8]; }
        if (s3 < thr) { insert9(dk, ik, s3, gbase + jj + 3); thr = dk[8]; }
      }
    }
    __syncthreads();   // vmcnt(0) drain -> cs(ct+1) resident; scoreT consumed
  }

  // ---- merge 4 quarter top-9s per query (lexicographic tie-break) ----
  float* mD = scoreT;                        // 3*64*9 = 1728 floats
  int*   mI = (int*)(scoreT + 1728);         // 1728 ints
  int*   fI = (int*)(scoreT + 3456);         // 576 ints (fits: 4352 total)
  if (quarter > 0) {
    int base = (quarter - 1) * 576 + q * 9;
#pragma unroll
    for (int k = 0; k < 9; ++k) { mD[base + k] = dk[k]; mI[base + k] = ik[k]; }
  }
  __syncthreads();
  if (quarter == 0) {
#pragma unroll 1
    for (int qq = 0; qq < 3; ++qq) {
      int base = qq * 576 + q * 9;
#pragma unroll 1
      for (int k = 0; k < 9; ++k)
        insert9_lex(dk, ik, mD[base + k], mI[base + k]);
    }
#pragma unroll
    for (int k = 0; k < 9; ++k) fI[q * 9 + k] = ik[k];
  }
  __syncthreads();

  // ---- aggregation: agg[q,c] = max_k h[nbr_k][c] - h[q][c] -> cat[:,128:256]
  int nb[9];
#pragma unroll
  for (int k = 0; k < 9; ++k) nb[k] = fI[q * 9 + k];
  long qrow = rowbase + q;
  const float4* cat4 = (const float4*)cat;
  float4* catw4 = (float4*)catw;
#pragma unroll 1
  for (int c4 = 0; c4 < 8; ++c4) {
    int cc = quarter * 8 + c4;
    float4 hq = cat4[qrow * 64 + cc];
    float4 mx = {-FLT_MAX, -FLT_MAX, -FLT_MAX, -FLT_MAX};
#pragma unroll
    for (int k = 0; k < 9; ++k) {
      float4 v = cat4[(brow + nb[k]) * 64 + cc];
      mx.x = fmaxf(mx.x, v.x - hq.x);
      mx.y = fmaxf(mx.y, v.y - hq.y);
      mx.z = fmaxf(mx.z, v.z - hq.z);
      mx.w = fmaxf(mx.w, v.w - hq.w);
    }
    catw4[qrow * 64 + 32 + cc] = mx;
  }
}

// ---------------------------------------------------------------------------
// BN + exact GELU (stage 2)
// ---------------------------------------------------------------------------
__global__ __launch_bounds__(256)
void bn_gelu_kernel(const float* __restrict__ X, const float* __restrict__ sum,
                    const float* __restrict__ sumsq, const float* __restrict__ g,
                    const float* __restrict__ be, float* __restrict__ out) {
  int gid = blockIdx.x * 256 + threadIdx.x;
  int row = gid >> 5;
  int c4 = (gid & 31) * 4;
  const float inv = 1.0f / (float)MROWS;
  float4 x  = *(const float4*)&X[(long)row * CC + c4];
  float4 sm = *(const float4*)&sum[c4];
  float4 sq = *(const float4*)&sumsq[c4];
  float4 gv = *(const float4*)&g[c4];
  float4 bv = *(const float4*)&be[c4];
  float xv[4] = {x.x, x.y, x.z, x.w};
  float smv[4] = {sm.x, sm.y, sm.z, sm.w};
  float sqv2[4] = {sq.x, sq.y, sq.z, sq.w};
  float ga[4] = {gv.x, gv.y, gv.z, gv.w};
  float ba[4] = {bv.x, bv.y, bv.z, bv.w};
  float o[4];
#pragma unroll
  for (int e = 0; e < 4; ++e) {
    float m = smv[e] * inv;
    float v = sqv2[e] * inv - m * m;
    float sc = ga[e] * rsqrtf(v + EPSBN);
    float h = (xv[e] - m) * sc + ba[e];
    o[e] = 0.5f * h * (1.0f + erff(h * 0.70710678118654752f));
  }
  float4 ov = {o[0], o[1], o[2], o[3]};
  *(float4*)&out[(long)row * CC + c4] = ov;
}

// ---------------------------------------------------------------------------
// BN + residual (stage 3) -> d_out
// ---------------------------------------------------------------------------
__global__ __launch_bounds__(256)
void bn_res_kernel(const float* __restrict__ X, const float* __restrict__ sum,
                   const float* __restrict__ sumsq, const float* __restrict__ g,
                   const float* __restrict__ be, const float* __restrict__ xres,
                   float* __restrict__ out) {
  int gid = blockIdx.x * 256 + threadIdx.x;
  int row = gid >> 5;
  int c4 = (gid & 31) * 4;
  const float inv = 1.0f / (float)MROWS;
  float4 x  = *(const float4*)&X[(long)row * CC + c4];
  float4 rr = *(const float4*)&xres[(long)row * CC + c4];
  float4 sm = *(const float4*)&sum[c4];
  float4 sq = *(const float4*)&sumsq[c4];
  float4 gv = *(const float4*)&g[c4];
  float4 bv = *(const float4*)&be[c4];
  float xv[4] = {x.x, x.y, x.z, x.w};
  float rv[4] = {rr.x, rr.y, rr.z, rr.w};
  float smv[4] = {sm.x, sm.y, sm.z, sm.w};
  float sqv2[4] = {sq.x, sq.y, sq.z, sq.w};
  float ga[4] = {gv.x, gv.y, gv.z, gv.w};
  float ba[4] = {bv.x, bv.y, bv.z, bv.w};
  float o[4];
#pragma unroll
  for (int e = 0; e < 4; ++e) {
    float m = smv[e] * inv;
    float v = sqv2[e] * inv - m * m;
    float sc = ga[e] * rsqrtf(v + EPSBN);
    o[e] = (xv[e] - m) * sc + ba[e] + rv[e];
  }
  float4 ov = {o[0], o[1], o[2], o[3]};
  *(float4*)&out[(long)row * CC + c4] = ov;
}

// ---------------------------------------------------------------------------
extern "C" void kernel_launch(void* const* d_in, const int* in_sizes, int n_in,
                              void* d_out, int out_size, void* d_ws, size_t ws_size,
                              hipStream_t stream) {
  const float* x   = (const float*)d_in[0];
  const float* W1  = (const float*)d_in[1];
  const float* b1  = (const float*)d_in[2];
  const float* g1  = (const float*)d_in[3];
  const float* be1 = (const float*)d_in[4];
  const float* Wg  = (const float*)d_in[5];
  const float* bg  = (const float*)d_in[6];
  const float* ggp = (const float*)d_in[7];
  const float* beg = (const float*)d_in[8];
  const float* W2  = (const float*)d_in[9];
  const float* b2  = (const float*)d_in[10];
  const float* g2  = (const float*)d_in[11];
  const float* be2 = (const float*)d_in[12];
  float* out = (float*)d_out;

  char* p = (char*)d_ws;
  auto alloc = [&](size_t bytes) {
    char* r = p;
    p += (bytes + 255) & ~(size_t)255;
    return r;
  };
  float*  bufA = (float*)alloc((size_t)MROWS * CC * 4);    // h_pre / hg_pre / out_pre
  float*  cat  = (float*)alloc((size_t)MROWS * 256 * 4);   // [h | agg]
  ushort* hHi  = (ushort*)alloc((size_t)MROWS * CC * 2);
  ushort* hLo  = (ushort*)alloc((size_t)MROWS * CC * 2);
  float*  sqv  = (float*)alloc((size_t)MROWS * 4);
  float*  hg   = (float*)alloc((size_t)MROWS * CC * 4);
  float*  stats = (float*)alloc(6 * CC * 4);
  float* sum1 = stats,       *ss1 = stats + 128;
  float* sum2 = stats + 256, *ss2 = stats + 384;
  float* sum3 = stats + 512, *ss3 = stats + 640;

  hipMemsetAsync(stats, 0, 6 * CC * 4, stream);

  // fc1 (+fused col stats) + BN -> h + bf16 hi/lo split + row norms
  gemm_bias_stats_kernel<<<MROWS / GBM, 256, 0, stream>>>(x, W1, b1, bufA, MROWS, CC, sum1, ss1);
  bn_split_kernel<<<MROWS / 8, 256, 0, stream>>>(bufA, sum1, ss1, g1, be1, cat, hHi, hLo, sqv);

  // KNN (split-bf16 MFMA distances, 3-pass) + top-9 + max-rel agg -> cat[:,128:]
  knn_agg_kernel<<<512, 256, 0, stream>>>(hHi, hLo, sqv, cat, cat);

  // graph MLP: cat @ Wg (+stats) + BN + GELU
  gemm_bias_stats_kernel<<<MROWS / GBM, 256, 0, stream>>>(cat, Wg, bg, bufA, MROWS, 2 * CC, sum2, ss2);
  bn_gelu_kernel<<<MROWS / 8, 256, 0, stream>>>(bufA, sum2, ss2, ggp, beg, hg);

  // fc2 (+stats) + BN + residual
  gemm_bias_stats_kernel<<<MROWS / GBM, 256, 0, stream>>>(hg, W2, b2, bufA, MROWS, CC, sum3, ss3);
  bn_res_kernel<<<MROWS / 8, 256, 0, stream>>>(bufA, sum3, ss3, g2, be2, x, out);
}